// Round 1
// baseline (8585.290 us; speedup 1.0000x reference)
//
#include <hip/hip_runtime.h>
#include <hip/hip_bf16.h>

#define VOCAB  32000
#define EMBED  256
#define HIDDEN 1024
#define G4     (4 * HIDDEN)   // 4096
#define BATCH  64
#define SEQ    256

// ---------------------------------------------------------------------------
// Kernel 1: x_gates[t][b][n] = b_ih[n] + b_hh[n] + sum_e embed[x[b,t]][e] * W_ih[n][e]
// GEMM M=T*B (block row = one t, 64 b's), N=4096, K=256. 64x64 tile, 16x16
// threads, 4x4 micro (strided: rows ty+16i, cols tx+16j), float4 LDS reads.
// ---------------------------------------------------------------------------
__global__ __launch_bounds__(256) void lstm_xgates(
    const int* __restrict__ x,           // [B, T]
    const float* __restrict__ emb,       // [VOCAB, EMBED]
    const float* __restrict__ W_ih,      // [G4, EMBED]
    const float* __restrict__ b_ih,
    const float* __restrict__ b_hh,
    float* __restrict__ xg)              // [T, B, G4]
{
    const int t   = blockIdx.y;
    const int n0  = blockIdx.x * 64;
    const int tid = threadIdx.x;
    const int ty  = tid >> 4;
    const int tx  = tid & 15;

    __shared__ float As[64][36];   // emb rows   (k-major, stride 144B = 16B aligned)
    __shared__ float Bs[64][36];   // W_ih rows
    __shared__ int   ridx[64];

    if (tid < 64) ridx[tid] = x[tid * SEQ + t];
    __syncthreads();

    float acc[4][4];
#pragma unroll
    for (int i = 0; i < 4; ++i)
#pragma unroll
        for (int j = 0; j < 4; ++j) acc[i][j] = 0.f;

    const int lr = tid >> 2;          // 0..63
    const int lc = (tid & 3) * 8;     // 0,8,16,24
    const float* abase = emb + (long)ridx[lr] * EMBED + lc;
    const float* bbase = W_ih + (long)(n0 + lr) * EMBED + lc;

    for (int k0 = 0; k0 < EMBED; k0 += 32) {
        *(float4*)&As[lr][lc]     = *(const float4*)(abase + k0);
        *(float4*)&As[lr][lc + 4] = *(const float4*)(abase + k0 + 4);
        *(float4*)&Bs[lr][lc]     = *(const float4*)(bbase + k0);
        *(float4*)&Bs[lr][lc + 4] = *(const float4*)(bbase + k0 + 4);
        __syncthreads();

#pragma unroll
        for (int kk = 0; kk < 32; kk += 4) {
            float4 av[4], bv[4];
#pragma unroll
            for (int i = 0; i < 4; ++i) av[i] = *(const float4*)&As[ty + 16 * i][kk];
#pragma unroll
            for (int j = 0; j < 4; ++j) bv[j] = *(const float4*)&Bs[tx + 16 * j][kk];
#pragma unroll
            for (int i = 0; i < 4; ++i)
#pragma unroll
                for (int j = 0; j < 4; ++j)
                    acc[i][j] += av[i].x * bv[j].x + av[i].y * bv[j].y
                               + av[i].z * bv[j].z + av[i].w * bv[j].w;
        }
        __syncthreads();
    }

#pragma unroll
    for (int j = 0; j < 4; ++j) {
        const int n = n0 + tx + 16 * j;
        const float bias = b_ih[n] + b_hh[n];
#pragma unroll
        for (int i = 0; i < 4; ++i) {
            const int b = ty + 16 * i;
            xg[((long)t * BATCH + b) * G4 + n] = acc[i][j] + bias;
        }
    }
}

// ---------------------------------------------------------------------------
// Zero-init h0 and c (ws is poisoned 0xAA before every call).
// ---------------------------------------------------------------------------
__global__ void lstm_init(float* __restrict__ h0, float* __restrict__ c)
{
    const int i = blockIdx.x * blockDim.x + threadIdx.x;
    if (i < BATCH * HIDDEN) { h0[i] = 0.f; c[i] = 0.f; }
}

// ---------------------------------------------------------------------------
// Kernel 2 (x256): one LSTM step.
// z[b, r] = xg_t[b, r] + sum_k h_in[b,k] * W_hh[r,k]; gates; update c, h_out.
// Block = 4 hidden units x 4 gates (16 W rows) x all 64 batches. Grid 256.
// 2x2 micro per thread (rows ty+8ri, b tx+32bi), 64-wide k-tiles in LDS.
// ---------------------------------------------------------------------------
__global__ __launch_bounds__(256) void lstm_step(
    const float* __restrict__ W_hh,    // [G4, HIDDEN]
    const float* __restrict__ xg_t,    // [B, G4] slice for this t
    const float* __restrict__ h_in,    // [B, H]
    float* __restrict__ h_out,         // [B, H]
    float* __restrict__ c)             // [B, H]
{
    const int j0  = blockIdx.x * 4;
    const int tid = threadIdx.x;
    const int ty  = tid >> 5;          // 0..7
    const int tx  = tid & 31;          // 0..31

    __shared__ float Wt[16][68];       // 272B stride, 16B aligned
    __shared__ float Ht[64][68];
    __shared__ float Zs[16][65];

    float acc[2][2] = {{0.f, 0.f}, {0.f, 0.f}};

    // loader mappings
    const int wr = tid >> 4;               // 0..15 (W tile row)
    const int wc = (tid & 15) * 4;         // 0..60
    const int hr = tid >> 2;               // 0..63 (h tile row = batch)
    const int hc = (tid & 3) * 16;         // 0,16,32,48
    const int grow_ld = (wr >> 2) * HIDDEN + j0 + (wr & 3);   // global W_hh row
    const float* wbase = W_hh + (long)grow_ld * HIDDEN + wc;
    const float* hbase = h_in + (long)hr * HIDDEN + hc;

    for (int k0 = 0; k0 < HIDDEN; k0 += 64) {
        *(float4*)&Wt[wr][wc]      = *(const float4*)(wbase + k0);
        *(float4*)&Ht[hr][hc]      = *(const float4*)(hbase + k0);
        *(float4*)&Ht[hr][hc + 4]  = *(const float4*)(hbase + k0 + 4);
        *(float4*)&Ht[hr][hc + 8]  = *(const float4*)(hbase + k0 + 8);
        *(float4*)&Ht[hr][hc + 12] = *(const float4*)(hbase + k0 + 12);
        __syncthreads();

#pragma unroll
        for (int kk = 0; kk < 64; kk += 4) {
            float4 wv[2], hv[2];
            wv[0] = *(const float4*)&Wt[ty][kk];
            wv[1] = *(const float4*)&Wt[ty + 8][kk];
            hv[0] = *(const float4*)&Ht[tx][kk];
            hv[1] = *(const float4*)&Ht[tx + 32][kk];
#pragma unroll
            for (int ri = 0; ri < 2; ++ri)
#pragma unroll
                for (int bi = 0; bi < 2; ++bi)
                    acc[ri][bi] += wv[ri].x * hv[bi].x + wv[ri].y * hv[bi].y
                                 + wv[ri].z * hv[bi].z + wv[ri].w * hv[bi].w;
        }
        __syncthreads();
    }

    // z = acc + xg, stash in LDS
#pragma unroll
    for (int ri = 0; ri < 2; ++ri) {
        const int r = ty + 8 * ri;
        const int grow = (r >> 2) * HIDDEN + j0 + (r & 3);
#pragma unroll
        for (int bi = 0; bi < 2; ++bi) {
            const int b = tx + 32 * bi;
            Zs[r][b] = acc[ri][bi] + xg_t[(long)b * G4 + grow];
        }
    }
    __syncthreads();

    // gate combine: thread = (jj, b)
    {
        const int jj = tid >> 6;     // 0..3
        const int b  = tid & 63;
        const float zi = Zs[jj][b];
        const float zf = Zs[4 + jj][b];
        const float zg = Zs[8 + jj][b];
        const float zo = Zs[12 + jj][b];
        const float ig = 1.f / (1.f + __expf(-zi));
        const float fg = 1.f / (1.f + __expf(-zf));
        const float gg = tanhf(zg);
        const float og = 1.f / (1.f + __expf(-zo));
        const long ci = (long)b * HIDDEN + j0 + jj;
        const float cn = fg * c[ci] + ig * gg;
        c[ci] = cn;
        h_out[ci] = og * tanhf(cn);
    }
}

// ---------------------------------------------------------------------------
// Kernel 3: out[b][v] = fc_b[v] + sum_k h[b][k] * fc_W[v][k]
// Tile: 64 b (all) x 64 v. rows(i)=b=ty+16i, cols(j)=v=tx+16j so stores are
// contiguous across tx. K=1024 in 32-wide LDS tiles.
// ---------------------------------------------------------------------------
__global__ __launch_bounds__(256) void lstm_fc(
    const float* __restrict__ h,       // [B, H]
    const float* __restrict__ fc_W,    // [VOCAB, H]
    const float* __restrict__ fc_b,    // [VOCAB]
    float* __restrict__ out)           // [B, VOCAB]
{
    const int v0  = blockIdx.x * 64;
    const int tid = threadIdx.x;
    const int ty  = tid >> 4;
    const int tx  = tid & 15;

    __shared__ float Hs[64][36];
    __shared__ float Ws[64][36];

    float acc[4][4];
#pragma unroll
    for (int i = 0; i < 4; ++i)
#pragma unroll
        for (int j = 0; j < 4; ++j) acc[i][j] = 0.f;

    const int lr = tid >> 2;
    const int lc = (tid & 3) * 8;
    const float* hbase = h + (long)lr * HIDDEN + lc;
    const float* wbase = fc_W + (long)(v0 + lr) * HIDDEN + lc;

    for (int k0 = 0; k0 < HIDDEN; k0 += 32) {
        *(float4*)&Hs[lr][lc]     = *(const float4*)(hbase + k0);
        *(float4*)&Hs[lr][lc + 4] = *(const float4*)(hbase + k0 + 4);
        *(float4*)&Ws[lr][lc]     = *(const float4*)(wbase + k0);
        *(float4*)&Ws[lr][lc + 4] = *(const float4*)(wbase + k0 + 4);
        __syncthreads();

#pragma unroll
        for (int kk = 0; kk < 32; kk += 4) {
            float4 hv[4], wv[4];
#pragma unroll
            for (int i = 0; i < 4; ++i) hv[i] = *(const float4*)&Hs[ty + 16 * i][kk];
#pragma unroll
            for (int j = 0; j < 4; ++j) wv[j] = *(const float4*)&Ws[tx + 16 * j][kk];
#pragma unroll
            for (int i = 0; i < 4; ++i)
#pragma unroll
                for (int j = 0; j < 4; ++j)
                    acc[i][j] += hv[i].x * wv[j].x + hv[i].y * wv[j].y
                               + hv[i].z * wv[j].z + hv[i].w * wv[j].w;
        }
        __syncthreads();
    }

#pragma unroll
    for (int j = 0; j < 4; ++j) {
        const int v = v0 + tx + 16 * j;
        const float bias = fc_b[v];
#pragma unroll
        for (int i = 0; i < 4; ++i) {
            const int b = ty + 16 * i;
            out[(long)b * VOCAB + v] = acc[i][j] + bias;
        }
    }
}

// ---------------------------------------------------------------------------
extern "C" void kernel_launch(void* const* d_in, const int* in_sizes, int n_in,
                              void* d_out, int out_size, void* d_ws, size_t ws_size,
                              hipStream_t stream)
{
    const int*   x     = (const int*)d_in[0];
    const float* emb   = (const float*)d_in[1];
    const float* W_ih  = (const float*)d_in[2];
    const float* W_hh  = (const float*)d_in[3];
    const float* b_ih  = (const float*)d_in[4];
    const float* b_hh  = (const float*)d_in[5];
    const float* fc_W  = (const float*)d_in[6];
    const float* fc_b  = (const float*)d_in[7];
    float* out = (float*)d_out;

    // workspace layout (f32): xg [T*B*4H] | h0 | h1 | c
    float* xg = (float*)d_ws;
    float* h0 = xg + (long)SEQ * BATCH * G4;     // 67,108,864 floats in
    float* h1 = h0 + BATCH * HIDDEN;
    float* c  = h1 + BATCH * HIDDEN;

    lstm_xgates<<<dim3(G4 / 64, SEQ), 256, 0, stream>>>(x, emb, W_ih, b_ih, b_hh, xg);
    lstm_init<<<dim3(BATCH * HIDDEN / 256), 256, 0, stream>>>(h0, c);

    float* hb[2] = {h0, h1};
    for (int t = 0; t < SEQ; ++t) {
        lstm_step<<<dim3(HIDDEN / 4), 256, 0, stream>>>(
            W_hh, xg + (long)t * BATCH * G4, hb[t & 1], hb[(t + 1) & 1], c);
    }
    // T even -> final h is in h0
    lstm_fc<<<dim3(VOCAB / 64), 256, 0, stream>>>(h0, fc_W, fc_b, out);
}